// Round 1
// baseline (304.117 us; speedup 1.0000x reference)
//
#include <hip/hip_runtime.h>

typedef unsigned short u16;
typedef unsigned int   u32;
typedef unsigned long long u64;

using f32x4  = __attribute__((ext_vector_type(4))) float;
using bf16x8 = __attribute__((ext_vector_type(8))) __bf16;
using u16x8  = __attribute__((ext_vector_type(8))) u16;

#define LOG2E 1.4426950408889634f

// float -> bf16 with round-to-nearest-even
__device__ __forceinline__ u16 f2bf(float f) {
  u32 u = __builtin_bit_cast(u32, f);
  u32 r = u + 0x7fffu + ((u >> 16) & 1u);
  return (u16)(r >> 16);
}

// async global->LDS, 16B per lane; LDS dest = wave-uniform base + lane*16
__device__ __forceinline__ void gll16(const u16* g, u16* l) {
  __builtin_amdgcn_global_load_lds(
      (const __attribute__((address_space(1))) void*)g,
      (__attribute__((address_space(3))) void*)l, 16, 0, 0);
}

__device__ __forceinline__ bf16x8 ld_bf8(const u16* p) {
  return __builtin_bit_cast(bf16x8, *(const u16x8*)p);
}

__device__ __forceinline__ f32x4 mfma_bf16(bf16x8 a, bf16x8 b, f32x4 c) {
  return __builtin_amdgcn_mfma_f32_16x16x32_bf16(a, b, c, 0, 0, 0);
}

// ---------------- kernel 1: cast q,k,v fp32->bf16, clear mask flag --------
__global__ __launch_bounds__(256) void convert_acts(
    const float* __restrict__ q, const float* __restrict__ k,
    const float* __restrict__ v, u16* __restrict__ qb, u16* __restrict__ kb,
    u16* __restrict__ vb, int* flag) {
  int z = blockIdx.y;
  const float* src = z == 0 ? q : z == 1 ? k : v;
  u16* dst = z == 0 ? qb : z == 1 ? kb : vb;
  if (z == 0 && blockIdx.x == 0 && threadIdx.x == 0) *flag = 0;
  u64 i = ((u64)blockIdx.x * 256 + threadIdx.x) * 8;
  f32x4 a = *(const f32x4*)(src + i);
  f32x4 b = *(const f32x4*)(src + i + 4);
  u16x8 o;
  o[0] = f2bf(a[0]); o[1] = f2bf(a[1]); o[2] = f2bf(a[2]); o[3] = f2bf(a[3]);
  o[4] = f2bf(b[0]); o[5] = f2bf(b[1]); o[6] = f2bf(b[2]); o[7] = f2bf(b[3]);
  *(u16x8*)(dst + i) = o;
}

// ---------------- kernel 2: W -> W^T bf16 (n-major, k-contiguous) ---------
__global__ __launch_bounds__(256) void transpose_w(
    const float* __restrict__ wq, const float* __restrict__ wk,
    const float* __restrict__ wv, const float* __restrict__ wo,
    u16* __restrict__ wqT, u16* __restrict__ wkT, u16* __restrict__ wvT,
    u16* __restrict__ woT) {
  int z = blockIdx.z;
  const float* W = z == 0 ? wq : z == 1 ? wk : z == 2 ? wv : wo;
  u16* WT = z == 0 ? wqT : z == 1 ? wkT : z == 2 ? wvT : woT;
  __shared__ float tile[32][33];
  int x = threadIdx.x, y = threadIdx.y;  // block (32,8)
  int c0 = blockIdx.x * 32, r0 = blockIdx.y * 32;
#pragma unroll
  for (int j = 0; j < 4; ++j)
    tile[y + j * 8][x] = W[(u64)(r0 + y + j * 8) * 1024 + c0 + x];
  __syncthreads();
#pragma unroll
  for (int j = 0; j < 4; ++j)
    WT[(u64)(c0 + y + j * 8) * 1024 + r0 + x] = f2bf(tile[x][y + j * 8]);
}

// ---------------- kernel 3: mask nonzero? ---------------------------------
__global__ __launch_bounds__(256) void mask_scan(const float* __restrict__ mask,
                                                 int* flag) {
  u64 i = ((u64)blockIdx.x * 256 + threadIdx.x) * 4;
  f32x4 m = *(const f32x4*)(mask + i);
  if (m[0] != 0.f || m[1] != 0.f || m[2] != 0.f || m[3] != 0.f)
    atomicOr(flag, 1);
}

// ---------------- shared GEMM core (m97 structure, swizzled LDS) ----------
// C[128x128] tile at (m0,n0): C = A[4096x1024] * Wt[1024x1024]^T
__device__ __forceinline__ void gemm_core(const u16* __restrict__ A,
                                          const u16* __restrict__ Wt, int m0,
                                          int n0, u16* As, u16* Bs,
                                          f32x4 acc[4][4]) {
  int t = threadIdx.x, w = t >> 6, lane = t & 63;
  int quad = lane >> 4, l16 = lane & 15;
  int wr = w >> 1, wc = w & 1;
  int srow0 = w * 16 + (lane >> 2);
  for (int kt = 0; kt < 1024; kt += 32) {
#pragma unroll
    for (int j = 0; j < 2; ++j) {
      int row = j * 64 + srow0;
      int cc = (lane & 3) ^ (row & 3);  // XOR swizzle via global source addr
      gll16(A + (u64)(m0 + row) * 1024 + kt + cc * 8,
            &As[(j * 256 + w * 64 + lane) * 8]);
      gll16(Wt + (u64)(n0 + row) * 1024 + kt + cc * 8,
            &Bs[(j * 256 + w * 64 + lane) * 8]);
    }
    __syncthreads();
    bf16x8 af[4], bfr[4];
#pragma unroll
    for (int mi = 0; mi < 4; ++mi) {
      int r = wr * 64 + mi * 16 + l16;
      af[mi] = ld_bf8(&As[r * 32 + (quad ^ (r & 3)) * 8]);
    }
#pragma unroll
    for (int ni = 0; ni < 4; ++ni) {
      int r = wc * 64 + ni * 16 + l16;
      bfr[ni] = ld_bf8(&Bs[r * 32 + (quad ^ (r & 3)) * 8]);
    }
#pragma unroll
    for (int mi = 0; mi < 4; ++mi)
#pragma unroll
      for (int ni = 0; ni < 4; ++ni)
        acc[mi][ni] = mfma_bf16(af[mi], bfr[ni], acc[mi][ni]);
    __syncthreads();
  }
}

// ---------------- kernel 4: fused QKV projection --------------------------
__global__ __launch_bounds__(256) void qkv_gemm(
    const u16* __restrict__ qb, const u16* __restrict__ kb,
    const u16* __restrict__ vb, const u16* __restrict__ wqT,
    const u16* __restrict__ wkT, const u16* __restrict__ wvT,
    const float* __restrict__ bq, const float* __restrict__ bk,
    const float* __restrict__ bv, u16* __restrict__ Qh, u16* __restrict__ Kh,
    u16* __restrict__ VhT) {
  int z = blockIdx.z;
  const u16* A = z == 0 ? qb : z == 1 ? kb : vb;
  const u16* Wt = z == 0 ? wqT : z == 1 ? wkT : wvT;
  const float* bias = z == 0 ? bq : z == 1 ? bk : bv;
  int m0 = blockIdx.x * 128, n0 = blockIdx.y * 128;
  __shared__ u16 As[128 * 32], Bs[128 * 32];
  f32x4 acc[4][4] = {};
  gemm_core(A, Wt, m0, n0, As, Bs, acc);
  int t = threadIdx.x, w = t >> 6, lane = t & 63;
  int quad = lane >> 4, l16 = lane & 15;
  int wr = w >> 1, wc = w & 1;
#pragma unroll
  for (int mi = 0; mi < 4; ++mi) {
#pragma unroll
    for (int ni = 0; ni < 4; ++ni) {
      int gn = n0 + wc * 64 + ni * 16 + l16;
      int h = gn >> 6, d = gn & 63;
      float bv_ = bias[gn];
#pragma unroll
      for (int r = 0; r < 4; ++r) {
        int gm = m0 + wr * 64 + mi * 16 + quad * 4 + r;
        int b = gm >> 11, s = gm & 2047;
        float val = acc[mi][ni][r] + bv_;
        if (z == 0)  // fold 1/sqrt(depth) and log2(e) into Q
          Qh[((u64)(b * 16 + h) * 2048 + s) * 64 + d] =
              f2bf(val * (LOG2E / 8.f));
        else if (z == 1)
          Kh[((u64)(b * 16 + h) * 2048 + s) * 64 + d] = f2bf(val);
        else  // V stored transposed: [bh][d][s]
          VhT[((u64)(b * 16 + h) * 64 + d) * 2048 + s] = f2bf(val);
      }
    }
  }
}

// ---------------- kernel 5: flash attention -------------------------------
// block: (q-tile of 64 rows) x (one bh); 4 waves, each 16 q-rows.
__global__ __launch_bounds__(256) void flash_attn(
    const u16* __restrict__ Qh, const u16* __restrict__ Kh,
    const u16* __restrict__ VhT, const float* __restrict__ mask,
    const int* __restrict__ flag, u16* __restrict__ Ob) {
  int bh = blockIdx.y, q0 = blockIdx.x * 64;
  int t = threadIdx.x, w = t >> 6, lane = t & 63;
  int quad = lane >> 4, l16 = lane & 15;
  __shared__ u16 Ks[128 * 64];    // [kv][d], swizzled 8-chunk rows
  __shared__ u16 Vt[64 * 128];    // [d][kv], swizzled 16-chunk rows
  __shared__ u16 Ps[4][16 * 136]; // per-wave P, padded rows (+8)
  // Q fragments held in registers for whole kernel (A-layout)
  const u16* Qbase = Qh + ((u64)bh * 2048 + q0 + w * 16 + l16) * 64 + quad * 8;
  bf16x8 aq0 = ld_bf8(Qbase);
  bf16x8 aq1 = ld_bf8(Qbase + 32);
  f32x4 o[4] = {};
  float m_r[4] = {-1e30f, -1e30f, -1e30f, -1e30f};
  float l_r[4] = {};
  const bool use_mask = (*flag) != 0;
  int cbase = w * 64 + lane;
  for (int kv0 = 0; kv0 < 2048; kv0 += 128) {
#pragma unroll
    for (int rnd = 0; rnd < 4; ++rnd) {
      int c = rnd * 256 + cbase;
      int kr = c >> 3, ksl = c & 7;
      gll16(Kh + ((u64)bh * 2048 + kv0 + kr) * 64 + (ksl ^ (kr & 7)) * 8,
            &Ks[c * 8]);
      int vr = c >> 4, vsl = c & 15;
      gll16(VhT + ((u64)bh * 64 + vr) * 2048 + kv0 + (vsl ^ (vr & 15)) * 8,
            &Vt[c * 8]);
    }
    __syncthreads();
    // S = Q K^T (already in log2 domain via Q scaling)
    f32x4 sv[8];
#pragma unroll
    for (int nt = 0; nt < 8; ++nt) {
      int n = nt * 16 + l16;
      bf16x8 b0 = ld_bf8(&Ks[n * 64 + ((quad) ^ (n & 7)) * 8]);
      bf16x8 b1 = ld_bf8(&Ks[n * 64 + ((quad + 4) ^ (n & 7)) * 8]);
      f32x4 s_ = {};
      s_ = mfma_bf16(aq0, b0, s_);
      s_ = mfma_bf16(aq1, b1, s_);
      sv[nt] = s_;
    }
    if (use_mask) {
#pragma unroll
      for (int nt = 0; nt < 8; ++nt)
#pragma unroll
        for (int r = 0; r < 4; ++r)
          sv[nt][r] += mask[(u64)(q0 + w * 16 + quad * 4 + r) * 2048 + kv0 +
                            nt * 16 + l16] *
                       (-1e9f * LOG2E);
    }
    // online softmax: rows live at (quad*4+r), cols at lane&15
    float mx[4];
#pragma unroll
    for (int r = 0; r < 4; ++r) {
      float m_ = sv[0][r];
#pragma unroll
      for (int nt = 1; nt < 8; ++nt) m_ = fmaxf(m_, sv[nt][r]);
      mx[r] = m_;
    }
#pragma unroll
    for (int off = 1; off < 16; off <<= 1)
#pragma unroll
      for (int r = 0; r < 4; ++r) mx[r] = fmaxf(mx[r], __shfl_xor(mx[r], off));
    float alpha[4], rs[4];
#pragma unroll
    for (int r = 0; r < 4; ++r) {
      float mnew = fmaxf(m_r[r], mx[r]);
      alpha[r] = exp2f(m_r[r] - mnew);
      m_r[r] = mnew;
      rs[r] = 0.f;
    }
#pragma unroll
    for (int nt = 0; nt < 8; ++nt)
#pragma unroll
      for (int r = 0; r < 4; ++r) {
        float p = exp2f(sv[nt][r] - m_r[r]);
        rs[r] += p;
        Ps[w][(quad * 4 + r) * 136 + nt * 16 + l16] = f2bf(p);
      }
#pragma unroll
    for (int off = 1; off < 16; off <<= 1)
#pragma unroll
      for (int r = 0; r < 4; ++r) rs[r] += __shfl_xor(rs[r], off);
#pragma unroll
    for (int r = 0; r < 4; ++r) l_r[r] = l_r[r] * alpha[r] + rs[r];
#pragma unroll
    for (int nt = 0; nt < 4; ++nt)
#pragma unroll
      for (int r = 0; r < 4; ++r) o[nt][r] *= alpha[r];
    // PV: P from LDS in A-layout, V^T fragments in B-layout
#pragma unroll
    for (int ks = 0; ks < 4; ++ks) {
      bf16x8 pf = ld_bf8(&Ps[w][l16 * 136 + ks * 32 + quad * 8]);
#pragma unroll
      for (int nt = 0; nt < 4; ++nt) {
        int n = nt * 16 + l16;
        bf16x8 vf = ld_bf8(&Vt[n * 128 + ((quad + ks * 4) ^ (n & 15)) * 8]);
        o[nt] = mfma_bf16(pf, vf, o[nt]);
      }
    }
    __syncthreads();
  }
  int b = bh >> 4, h = bh & 15;
#pragma unroll
  for (int nt = 0; nt < 4; ++nt)
#pragma unroll
    for (int r = 0; r < 4; ++r) {
      int srow = q0 + w * 16 + quad * 4 + r;
      float val = o[nt][r] / l_r[r];
      Ob[(u64)(b * 2048 + srow) * 1024 + h * 64 + nt * 16 + l16] = f2bf(val);
    }
}

// ---------------- kernel 6: output projection -----------------------------
__global__ __launch_bounds__(256) void out_gemm(const u16* __restrict__ Ob,
                                                const u16* __restrict__ woT,
                                                const float* __restrict__ bo,
                                                float* __restrict__ out) {
  int m0 = blockIdx.x * 128, n0 = blockIdx.y * 128;
  __shared__ u16 As[128 * 32], Bs[128 * 32];
  f32x4 acc[4][4] = {};
  gemm_core(Ob, woT, m0, n0, As, Bs, acc);
  int t = threadIdx.x, w = t >> 6, lane = t & 63;
  int quad = lane >> 4, l16 = lane & 15;
  int wr = w >> 1, wc = w & 1;
#pragma unroll
  for (int mi = 0; mi < 4; ++mi) {
#pragma unroll
    for (int ni = 0; ni < 4; ++ni) {
      int gn = n0 + wc * 64 + ni * 16 + l16;
      float bv_ = bo[gn];
#pragma unroll
      for (int r = 0; r < 4; ++r) {
        int gm = m0 + wr * 64 + mi * 16 + quad * 4 + r;
        out[(u64)gm * 1024 + gn] = acc[mi][ni][r] + bv_;
      }
    }
  }
}

extern "C" void kernel_launch(void* const* d_in, const int* in_sizes, int n_in,
                              void* d_out, int out_size, void* d_ws,
                              size_t ws_size, hipStream_t stream) {
  const float* q = (const float*)d_in[0];
  const float* k = (const float*)d_in[1];
  const float* v = (const float*)d_in[2];
  const float* mask = (const float*)d_in[3];
  const float* wq = (const float*)d_in[4];
  const float* bq = (const float*)d_in[5];
  const float* wk = (const float*)d_in[6];
  const float* bk = (const float*)d_in[7];
  const float* wv = (const float*)d_in[8];
  const float* bv = (const float*)d_in[9];
  const float* wo = (const float*)d_in[10];
  const float* bo = (const float*)d_in[11];
  float* out = (float*)d_out;
  char* ws = (char*)d_ws;
  const u64 MB = 1ull << 20;
  u16* qb = (u16*)(ws + 0 * MB);   // 8 MB (reused as attn output later)
  u16* kb = (u16*)(ws + 8 * MB);   // 8 MB
  u16* vb = (u16*)(ws + 16 * MB);  // 8 MB
  u16* wqT = (u16*)(ws + 24 * MB);
  u16* wkT = (u16*)(ws + 26 * MB);
  u16* wvT = (u16*)(ws + 28 * MB);
  u16* woT = (u16*)(ws + 30 * MB);
  u16* Qh = (u16*)(ws + 32 * MB);   // [32][2048][64] bf16
  u16* Kh = (u16*)(ws + 40 * MB);   // [32][2048][64]
  u16* VhT = (u16*)(ws + 48 * MB);  // [32][64][2048]
  int* flag = (int*)(ws + 56 * MB);
  u16* Ob = qb;  // alias: qb dead after qkv_gemm

  convert_acts<<<dim3(2048, 3), 256, 0, stream>>>(q, k, v, qb, kb, vb, flag);
  transpose_w<<<dim3(32, 32, 4), dim3(32, 8), 0, stream>>>(
      wq, wk, wv, wo, wqT, wkT, wvT, woT);
  mask_scan<<<dim3(4096), 256, 0, stream>>>(mask, flag);
  qkv_gemm<<<dim3(32, 8, 3), 256, 0, stream>>>(qb, kb, vb, wqT, wkT, wvT, bq,
                                               bk, bv, Qh, Kh, VhT);
  flash_attn<<<dim3(32, 32), 256, 0, stream>>>(Qh, Kh, VhT, mask, flag, Ob);
  out_gemm<<<dim3(32, 8), 256, 0, stream>>>(Ob, woT, bo, out);
}

// Round 2
// 291.633 us; speedup vs baseline: 1.0428x; 1.0428x over previous
//
#include <hip/hip_runtime.h>

typedef unsigned short u16;
typedef unsigned int   u32;
typedef unsigned long long u64;
typedef short s16;

using f32x4  = __attribute__((ext_vector_type(4))) float;
using bf16x8 = __attribute__((ext_vector_type(8))) __bf16;
using u16x8  = __attribute__((ext_vector_type(8))) u16;
using u16x4  = __attribute__((ext_vector_type(4))) u16;
using s16x4  = __attribute__((ext_vector_type(4))) s16;

#define LOG2E 1.4426950408889634f

// float -> bf16 with round-to-nearest-even
__device__ __forceinline__ u16 f2bf(float f) {
  u32 u = __builtin_bit_cast(u32, f);
  u32 r = u + 0x7fffu + ((u >> 16) & 1u);
  return (u16)(r >> 16);
}

// async global->LDS, 16B per lane; LDS dest = wave-uniform base + lane*16
__device__ __forceinline__ void gll16(const u16* g, u16* l) {
  __builtin_amdgcn_global_load_lds(
      (const __attribute__((address_space(1))) void*)g,
      (__attribute__((address_space(3))) void*)l, 16, 0, 0);
}

__device__ __forceinline__ bf16x8 ld_bf8(const u16* p) {
  return __builtin_bit_cast(bf16x8, *(const u16x8*)p);
}

__device__ __forceinline__ f32x4 mfma32(bf16x8 a, bf16x8 b, f32x4 c) {
  return __builtin_amdgcn_mfma_f32_16x16x32_bf16(a, b, c, 0, 0, 0);
}

// PV step: A = 4 bf16 (k=quad*4+j), B = 4 bf16, 16x16x16 MFMA.
#if __has_builtin(__builtin_amdgcn_mfma_f32_16x16x16bf16_1k)
__device__ __forceinline__ f32x4 pv_mfma(u16x4 a, u16x4 b, f32x4 c) {
  return __builtin_amdgcn_mfma_f32_16x16x16bf16_1k(
      __builtin_bit_cast(s16x4, a), __builtin_bit_cast(s16x4, b), c, 0, 0, 0);
}
#else
// fallback: zero-pad to K=32 (values at k=quad*8+j, j<4 on both operands)
__device__ __forceinline__ f32x4 pv_mfma(u16x4 a, u16x4 b, f32x4 c) {
  u16x8 a8 = {a[0], a[1], a[2], a[3], 0, 0, 0, 0};
  u16x8 b8 = {b[0], b[1], b[2], b[3], 0, 0, 0, 0};
  return mfma32(__builtin_bit_cast(bf16x8, a8),
                __builtin_bit_cast(bf16x8, b8), c);
}
#endif

// ------------- kernel 1: fused convert + weight transpose + mask scan -----
// grid (2048, 5): y<3 convert q/k/v; y==3 transpose 4 weights; y==4 mask
__global__ __launch_bounds__(256) void pre_kernel(
    const float* __restrict__ q, const float* __restrict__ k,
    const float* __restrict__ v, const float* __restrict__ mask,
    const float* __restrict__ wq, const float* __restrict__ wk,
    const float* __restrict__ wv, const float* __restrict__ wo,
    u16* __restrict__ qb, u16* __restrict__ kb, u16* __restrict__ vb,
    u16* __restrict__ wqT, u16* __restrict__ wkT, u16* __restrict__ wvT,
    u16* __restrict__ woT, int* flag) {
  int y = blockIdx.y, t = threadIdx.x;
  if (y < 3) {
    const float* src = y == 0 ? q : y == 1 ? k : v;
    u16* dst = y == 0 ? qb : y == 1 ? kb : vb;
    u64 i = ((u64)blockIdx.x * 256 + t) * 8;
    f32x4 a = *(const f32x4*)(src + i);
    f32x4 b = *(const f32x4*)(src + i + 4);
    u16x8 o;
    o[0] = f2bf(a[0]); o[1] = f2bf(a[1]); o[2] = f2bf(a[2]); o[3] = f2bf(a[3]);
    o[4] = f2bf(b[0]); o[5] = f2bf(b[1]); o[6] = f2bf(b[2]); o[7] = f2bf(b[3]);
    *(u16x8*)(dst + i) = o;
  } else if (y == 3) {
    __shared__ float tile[32][33];
    int x = t & 31, yy = t >> 5;  // 32 x 8
#pragma unroll
    for (int rep = 0; rep < 2; ++rep) {
      int job = blockIdx.x * 2 + rep;
      int z = job >> 10, tt = job & 1023;
      const float* W = z == 0 ? wq : z == 1 ? wk : z == 2 ? wv : wo;
      u16* WT = z == 0 ? wqT : z == 1 ? wkT : z == 2 ? wvT : woT;
      int c0 = (tt & 31) * 32, r0 = (tt >> 5) * 32;
#pragma unroll
      for (int j = 0; j < 4; ++j)
        tile[yy + j * 8][x] = W[(u64)(r0 + yy + j * 8) * 1024 + c0 + x];
      __syncthreads();
#pragma unroll
      for (int j = 0; j < 4; ++j)
        WT[(u64)(c0 + yy + j * 8) * 1024 + r0 + x] = f2bf(tile[x][yy + j * 8]);
      __syncthreads();
    }
  } else {
    u64 i = ((u64)blockIdx.x * 256 + t) * 8;
    f32x4 a = *(const f32x4*)(mask + i);
    f32x4 b = *(const f32x4*)(mask + i + 4);
    bool nz = a[0] != 0.f || a[1] != 0.f || a[2] != 0.f || a[3] != 0.f ||
              b[0] != 0.f || b[1] != 0.f || b[2] != 0.f || b[3] != 0.f;
    if (nz) atomicOr(flag, 1);
  }
}

// ---------------- shared GEMM core (m97 structure, swizzled LDS) ----------
__device__ __forceinline__ void gemm_core(const u16* __restrict__ A,
                                          const u16* __restrict__ Wt, int m0,
                                          int n0, u16* As, u16* Bs,
                                          f32x4 acc[4][4]) {
  int t = threadIdx.x, w = t >> 6, lane = t & 63;
  int quad = lane >> 4, l16 = lane & 15;
  int wr = w >> 1, wc = w & 1;
  int srow0 = w * 16 + (lane >> 2);
  for (int kt = 0; kt < 1024; kt += 32) {
#pragma unroll
    for (int j = 0; j < 2; ++j) {
      int row = j * 64 + srow0;
      int cc = (lane & 3) ^ (row & 3);  // XOR swizzle via global source addr
      gll16(A + (u64)(m0 + row) * 1024 + kt + cc * 8,
            &As[(j * 256 + w * 64 + lane) * 8]);
      gll16(Wt + (u64)(n0 + row) * 1024 + kt + cc * 8,
            &Bs[(j * 256 + w * 64 + lane) * 8]);
    }
    __syncthreads();
    bf16x8 af[4], bfr[4];
#pragma unroll
    for (int mi = 0; mi < 4; ++mi) {
      int r = wr * 64 + mi * 16 + l16;
      af[mi] = ld_bf8(&As[r * 32 + (quad ^ (r & 3)) * 8]);
    }
#pragma unroll
    for (int ni = 0; ni < 4; ++ni) {
      int r = wc * 64 + ni * 16 + l16;
      bfr[ni] = ld_bf8(&Bs[r * 32 + (quad ^ (r & 3)) * 8]);
    }
#pragma unroll
    for (int mi = 0; mi < 4; ++mi)
#pragma unroll
      for (int ni = 0; ni < 4; ++ni)
        acc[mi][ni] = mfma32(af[mi], bfr[ni], acc[mi][ni]);
    __syncthreads();
  }
}

// ---------------- kernel 2: fused QKV projection --------------------------
__global__ __launch_bounds__(256) void qkv_gemm(
    const u16* __restrict__ qb, const u16* __restrict__ kb,
    const u16* __restrict__ vb, const u16* __restrict__ wqT,
    const u16* __restrict__ wkT, const u16* __restrict__ wvT,
    const float* __restrict__ bq, const float* __restrict__ bk,
    const float* __restrict__ bv, u16* __restrict__ Qh, u16* __restrict__ Kh,
    u16* __restrict__ VhT) {
  int z = blockIdx.z;
  const u16* A = z == 0 ? qb : z == 1 ? kb : vb;
  const u16* Wt = z == 0 ? wqT : z == 1 ? wkT : wvT;
  const float* bias = z == 0 ? bq : z == 1 ? bk : bv;
  int m0 = blockIdx.x * 128, n0 = blockIdx.y * 128;
  __shared__ u16 As[128 * 32], Bs[128 * 32];
  f32x4 acc[4][4] = {};
  gemm_core(A, Wt, m0, n0, As, Bs, acc);
  int t = threadIdx.x, w = t >> 6, lane = t & 63;
  int quad = lane >> 4, l16 = lane & 15;
  int wr = w >> 1, wc = w & 1;
#pragma unroll
  for (int mi = 0; mi < 4; ++mi) {
#pragma unroll
    for (int ni = 0; ni < 4; ++ni) {
      int gn = n0 + wc * 64 + ni * 16 + l16;
      int h = gn >> 6, d = gn & 63;
      float bv_ = bias[gn];
#pragma unroll
      for (int r = 0; r < 4; ++r) {
        int gm = m0 + wr * 64 + mi * 16 + quad * 4 + r;
        int b = gm >> 11, s = gm & 2047;
        float val = acc[mi][ni][r] + bv_;
        if (z == 0)  // fold 1/sqrt(depth) and log2(e) into Q
          Qh[((u64)(b * 16 + h) * 2048 + s) * 64 + d] =
              f2bf(val * (LOG2E / 8.f));
        else if (z == 1)
          Kh[((u64)(b * 16 + h) * 2048 + s) * 64 + d] = f2bf(val);
        else  // V stored transposed: [bh][d][s]
          VhT[((u64)(b * 16 + h) * 64 + d) * 2048 + s] = f2bf(val);
      }
    }
  }
}

// ---------------- kernel 3: flash attention (S^T register trick) ----------
// block: 64 q-rows x one bh; 4 waves x 16 q-rows. Computes St = K Q^T in
// C-layout; that register layout IS the A-fragment of 16x16x16 MFMA for
// un-transposed S, so P feeds PV directly from registers (no LDS trip).
__global__ __launch_bounds__(256) void flash_attn(
    const u16* __restrict__ Qh, const u16* __restrict__ Kh,
    const u16* __restrict__ VhT, const float* __restrict__ mask,
    const int* __restrict__ flag, u16* __restrict__ Ob) {
  int bh = blockIdx.y, q0 = blockIdx.x * 64;
  int t = threadIdx.x, w = t >> 6, lane = t & 63;
  int quad = lane >> 4, l16 = lane & 15;
  __shared__ u16 Ks[1024 * 8];  // 16KB: [kv][d8 chunks, xor-swizzled]
  __shared__ u16 Vt[1024 * 8];  // 16KB: [h8=kv/8][d] 16B granules
  // Q fragments (B-operand): Q[q=l16][d=quad*8+j], two d-halves
  const u16* Qbase = Qh + ((u64)bh * 2048 + q0 + w * 16 + l16) * 64 + quad * 8;
  bf16x8 aq0 = ld_bf8(Qbase);
  bf16x8 aq1 = ld_bf8(Qbase + 32);
  f32x4 o[4] = {};
  float m_r = -1e30f, l_r = 0.f;  // per-lane: one q = l16
  const bool use_mask = (*flag) != 0;
  const u16* Kg0 = Kh + (u64)bh * 2048 * 64;
  const u16* Vg0 = VhT + (u64)bh * 64 * 2048;
  for (int kv0 = 0; kv0 < 2048; kv0 += 128) {
#pragma unroll
    for (int rnd = 0; rnd < 4; ++rnd) {
      int ci = rnd * 256 + t;
      int kv = ci >> 3, slot = ci & 7, d8 = slot ^ (kv & 7);
      gll16(Kg0 + (u64)(kv0 + kv) * 64 + d8 * 8, &Ks[ci * 8]);
      int h8 = ci >> 6, dd = ci & 63;
      gll16(Vg0 + (u64)dd * 2048 + kv0 + h8 * 8, &Vt[ci * 8]);
    }
    __syncthreads();
    // St chunks: St[kv=c*16+quad*4+r][q=l16] in C-layout
    f32x4 sv[8];
#pragma unroll
    for (int c = 0; c < 8; ++c) {
      int kvr = c * 16 + l16;
      bf16x8 k0 = ld_bf8(&Ks[(kvr * 8 + (quad ^ (kvr & 7))) * 8]);
      bf16x8 k1 = ld_bf8(&Ks[(kvr * 8 + ((quad + 4) ^ (kvr & 7))) * 8]);
      f32x4 s_ = {};
      s_ = mfma32(k0, aq0, s_);
      s_ = mfma32(k1, aq1, s_);
      sv[c] = s_;
    }
    if (use_mask) {
      int qg = q0 + w * 16 + l16;
#pragma unroll
      for (int c = 0; c < 8; ++c)
#pragma unroll
        for (int r = 0; r < 4; ++r)
          sv[c][r] += mask[(u64)qg * 2048 + kv0 + c * 16 + quad * 4 + r] *
                      (-1e9f * LOG2E);
    }
    // online softmax over kv for q=l16: 32 in-lane values + quads via xor
    float mx = sv[0][0];
#pragma unroll
    for (int c = 0; c < 8; ++c)
#pragma unroll
      for (int r = 0; r < 4; ++r) mx = fmaxf(mx, sv[c][r]);
    mx = fmaxf(mx, __shfl_xor(mx, 16));
    mx = fmaxf(mx, __shfl_xor(mx, 32));
    float mnew = fmaxf(m_r, mx);
    float alpha = exp2f(m_r - mnew);
    m_r = mnew;
    float rs = 0.f;
    u16x4 pk[8];
#pragma unroll
    for (int c = 0; c < 8; ++c)
#pragma unroll
      for (int r = 0; r < 4; ++r) {
        float p = exp2f(sv[c][r] - m_r);
        rs += p;
        pk[c][r] = f2bf(p);
      }
    rs += __shfl_xor(rs, 16);
    rs += __shfl_xor(rs, 32);
    l_r = l_r * alpha + rs;
    // broadcast alpha to the rows this lane accumulates (q = quad*4+r)
    float a4[4];
#pragma unroll
    for (int r = 0; r < 4; ++r)
      a4[r] = __shfl(alpha, (lane & 48) | (quad * 4 + r));
#pragma unroll
    for (int nt = 0; nt < 4; ++nt)
#pragma unroll
      for (int r = 0; r < 4; ++r) o[nt][r] *= a4[r];
    // PV: A = pk (registers), B = Vt granule reads (ds_read_b64)
#pragma unroll
    for (int c = 0; c < 8; ++c) {
      int hb = (c * 2 + (quad >> 1)) * 64;
      int half = (quad & 1) * 4;
#pragma unroll
      for (int nt = 0; nt < 4; ++nt) {
        u16x4 vf = *(const u16x4*)(&Vt[(hb + nt * 16 + l16) * 8 + half]);
        o[nt] = pv_mfma(pk[c], vf, o[nt]);
      }
    }
    __syncthreads();
  }
  int b = bh >> 4, h = bh & 15;
  float rl[4];
#pragma unroll
  for (int r = 0; r < 4; ++r)
    rl[r] = 1.f / __shfl(l_r, (lane & 48) | (quad * 4 + r));
#pragma unroll
  for (int nt = 0; nt < 4; ++nt)
#pragma unroll
    for (int r = 0; r < 4; ++r) {
      int srow = q0 + w * 16 + quad * 4 + r;
      Ob[(u64)(b * 2048 + srow) * 1024 + h * 64 + nt * 16 + l16] =
          f2bf(o[nt][r] * rl[r]);
    }
}

// ---------------- kernel 4: output projection -----------------------------
__global__ __launch_bounds__(256) void out_gemm(const u16* __restrict__ Ob,
                                                const u16* __restrict__ woT,
                                                const float* __restrict__ bo,
                                                float* __restrict__ out) {
  int m0 = blockIdx.x * 128, n0 = blockIdx.y * 128;
  __shared__ u16 As[128 * 32], Bs[128 * 32];
  f32x4 acc[4][4] = {};
  gemm_core(Ob, woT, m0, n0, As, Bs, acc);
  int t = threadIdx.x, w = t >> 6, lane = t & 63;
  int quad = lane >> 4, l16 = lane & 15;
  int wr = w >> 1, wc = w & 1;
#pragma unroll
  for (int mi = 0; mi < 4; ++mi) {
#pragma unroll
    for (int ni = 0; ni < 4; ++ni) {
      int gn = n0 + wc * 64 + ni * 16 + l16;
      float bv_ = bo[gn];
#pragma unroll
      for (int r = 0; r < 4; ++r) {
        int gm = m0 + wr * 64 + mi * 16 + quad * 4 + r;
        out[(u64)gm * 1024 + gn] = acc[mi][ni][r] + bv_;
      }
    }
  }
}

extern "C" void kernel_launch(void* const* d_in, const int* in_sizes, int n_in,
                              void* d_out, int out_size, void* d_ws,
                              size_t ws_size, hipStream_t stream) {
  const float* q = (const float*)d_in[0];
  const float* k = (const float*)d_in[1];
  const float* v = (const float*)d_in[2];
  const float* mask = (const float*)d_in[3];
  const float* wq = (const float*)d_in[4];
  const float* bq = (const float*)d_in[5];
  const float* wk = (const float*)d_in[6];
  const float* bk = (const float*)d_in[7];
  const float* wv = (const float*)d_in[8];
  const float* bv = (const float*)d_in[9];
  const float* wo = (const float*)d_in[10];
  const float* bo = (const float*)d_in[11];
  float* out = (float*)d_out;
  char* ws = (char*)d_ws;
  const u64 MB = 1ull << 20;
  u16* qb = (u16*)(ws + 0 * MB);   // 8 MB (reused as attn output later)
  u16* kb = (u16*)(ws + 8 * MB);   // 8 MB
  u16* vb = (u16*)(ws + 16 * MB);  // 8 MB
  u16* wqT = (u16*)(ws + 24 * MB);
  u16* wkT = (u16*)(ws + 26 * MB);
  u16* wvT = (u16*)(ws + 28 * MB);
  u16* woT = (u16*)(ws + 30 * MB);
  u16* Qh = (u16*)(ws + 32 * MB);   // [32][2048][64] bf16
  u16* Kh = (u16*)(ws + 40 * MB);   // [32][2048][64]
  u16* VhT = (u16*)(ws + 48 * MB);  // [32][64][2048]
  int* flag = (int*)(ws + 56 * MB);
  u16* Ob = qb;  // alias: qb dead after qkv_gemm

  hipMemsetAsync(flag, 0, 4, stream);
  pre_kernel<<<dim3(2048, 5), 256, 0, stream>>>(
      q, k, v, mask, wq, wk, wv, wo, qb, kb, vb, wqT, wkT, wvT, woT, flag);
  qkv_gemm<<<dim3(32, 8, 3), 256, 0, stream>>>(qb, kb, vb, wqT, wkT, wvT, bq,
                                               bk, bv, Qh, Kh, VhT);
  flash_attn<<<dim3(32, 32), 256, 0, stream>>>(Qh, Kh, VhT, mask, flag, Ob);
  out_gemm<<<dim3(32, 8), 256, 0, stream>>>(Ob, woT, bo, out);
}